// Round 1
// baseline (249.634 us; speedup 1.0000x reference)
//
#include <hip/hip_runtime.h>
#include <math.h>

#define H 1024
#define NB 5
#define IN 42
#define C_OUT 1000

__device__ __forceinline__ float sigmoidf_(float x) {
    return 1.0f / (1.0f + expf(-x));
}

__device__ __forceinline__ float wave_reduce_sum(float v) {
    #pragma unroll
    for (int off = 32; off > 0; off >>= 1) v += __shfl_xor(v, off);
    return v;
}

// ---------------------------------------------------------------------------
// Kernel 1: prepare input features xb[5][42] from x (1,133,2)
// ---------------------------------------------------------------------------
__global__ void prep_kernel(const float* __restrict__ x, float* __restrict__ xb) {
    __shared__ float slx[21], sly[21], srx[21], sry[21];
    int l = threadIdx.x;  // 64 threads, one wave
    if (l < 21) {
        slx[l] = x[(91 + l) * 2 + 0];
        sly[l] = x[(91 + l) * 2 + 1];
        srx[l] = x[(112 + l) * 2 + 0];
        sry[l] = x[(112 + l) * 2 + 1];
    }
    __syncthreads();

    // every thread computes the (tiny) reductions redundantly
    float lx_min = slx[0], lx_max = slx[0], ly_min = sly[0], ly_max = sly[0];
    float rx_min = srx[0], rx_max = srx[0], ry_min = sry[0], ry_max = sry[0];
    #pragma unroll
    for (int i = 1; i < 21; ++i) {
        lx_min = fminf(lx_min, slx[i]); lx_max = fmaxf(lx_max, slx[i]);
        ly_min = fminf(ly_min, sly[i]); ly_max = fmaxf(ly_max, sly[i]);
        rx_min = fminf(rx_min, srx[i]); rx_max = fmaxf(rx_max, srx[i]);
        ry_min = fminf(ry_min, sry[i]); ry_max = fmaxf(ry_max, sry[i]);
    }
    float w_l = lx_max - lx_min, h_l = ly_max - ly_min;
    float w_r = rx_max - rx_min, h_r = ry_max - ry_min;
    float w_b = x[5 * 2 + 0] - x[6 * 2 + 0];  // body[5,0] - body[6,0]
    float h_b = 4.0f * w_b;

    float sbx = x[0], sby = x[1];            // src_body = x0[0]
    float slx0 = slx[9], sly0 = sly[9];      // src_left = x0[100] = left[9]
    float srx0 = srx[9], sry0 = sry[9];      // src_right = x0[121] = right[9]

    bool cond_l = (w_l != 0.0f) && (h_l != 0.0f);
    bool cond_r = (w_r != 0.0f) && (h_r != 0.0f);
    bool cond_b = (w_b != 0.0f) && (h_b != 0.0f);
    float dlx = cond_l ? w_l : 1.0f, dly = cond_l ? h_l : 1.0f;
    float drx = cond_r ? w_r : 1.0f, dry = cond_r ? h_r : 1.0f;
    float wb  = cond_b ? w_b : 1.0f, hb  = cond_b ? h_b : 1.0f;

    if (l < 21) {
        float lx = slx[l], ly = sly[l], rx = srx[l], ry = sry[l];
        // branch 0: left normalized
        xb[0 * IN + 2 * l + 0] = (lx - slx0) / dlx;
        xb[0 * IN + 2 * l + 1] = (ly - sly0) / dly;
        // branch 1: right normalized
        xb[1 * IN + 2 * l + 0] = (rx - srx0) / drx;
        xb[1 * IN + 2 * l + 1] = (ry - sry0) / dry;
        // branch 2: f2l = (left - src_body) / [wb, 1]
        xb[2 * IN + 2 * l + 0] = (lx - sbx) / wb;
        xb[2 * IN + 2 * l + 1] = (ly - sby);
        // branch 3: f2r = (right - src_body) / [1, hb]
        xb[3 * IN + 2 * l + 0] = (rx - sbx);
        xb[3 * IN + 2 * l + 1] = (ry - sby) / hb;
        // branch 4: h2h = (left - right) / [wb, hb]
        xb[4 * IN + 2 * l + 0] = (lx - rx) / wb;
        xb[4 * IN + 2 * l + 1] = (ly - ry) / hb;
    }
}

// ---------------------------------------------------------------------------
// Kernel 2: layer0 LSTM cell (h=c=0): one wave per output element.
// g = W_ih0[b] @ xb[b] + b_ih0[b] + b_hh0[b]; f-gate unused (c=0).
// h0 = sigmoid(o) * tanh( sigmoid(i) * tanh(g) )
// ---------------------------------------------------------------------------
__global__ void layer0_kernel(const float* __restrict__ wih0,
                              const float* __restrict__ bih0,
                              const float* __restrict__ bhh0,
                              const float* __restrict__ xb,
                              float* __restrict__ h0out) {
    int wave = (blockIdx.x * blockDim.x + threadIdx.x) >> 6;  // 0..5119
    int lane = threadIdx.x & 63;
    int b = wave >> 10;        // branch
    int j = wave & (H - 1);    // output index within H

    float xv = (lane < IN) ? xb[b * IN + lane] : 0.0f;
    const float* Wb = wih0 + (size_t)b * 4 * H * IN;
    float gi = 0.0f, gg = 0.0f, go = 0.0f;
    if (lane < IN) {
        gi = Wb[(size_t)(j)         * IN + lane] * xv;
        gg = Wb[(size_t)(j + 2 * H) * IN + lane] * xv;
        go = Wb[(size_t)(j + 3 * H) * IN + lane] * xv;
    }
    gi = wave_reduce_sum(gi);
    gg = wave_reduce_sum(gg);
    go = wave_reduce_sum(go);
    if (lane == 0) {
        size_t base = (size_t)b * 4 * H;
        gi += bih0[base + j]         + bhh0[base + j];
        gg += bih0[base + j + 2 * H] + bhh0[base + j + 2 * H];
        go += bih0[base + j + 3 * H] + bhh0[base + j + 3 * H];
        float c2 = sigmoidf_(gi) * tanhf(gg);
        h0out[b * H + j] = sigmoidf_(go) * tanhf(c2);
    }
}

// ---------------------------------------------------------------------------
// Kernel 3: layer1 LSTM cell (h=c=0): one wave per output, 4 outputs/block.
// h0[b] staged in LDS. ctx = h1 (softmax over 1 element == 1).
// ---------------------------------------------------------------------------
__global__ void layer1_kernel(const float* __restrict__ wih1,
                              const float* __restrict__ bih1,
                              const float* __restrict__ bhh1,
                              const float* __restrict__ h0,
                              float* __restrict__ ctx) {
    __shared__ float4 hs[H / 4];  // 1024 floats
    int out0 = blockIdx.x * 4;            // first output of this block
    int b = out0 >> 10;                   // uniform per block (1024 % 4 == 0)
    hs[threadIdx.x] = ((const float4*)(h0 + b * H))[threadIdx.x];
    __syncthreads();

    int wave = threadIdx.x >> 6;
    int lane = threadIdx.x & 63;
    int out = out0 + wave;
    int j = out & (H - 1);

    const float* Wb = wih1 + (size_t)b * 4 * H * H;
    const float4* ri = (const float4*)(Wb + (size_t)(j)         * H);
    const float4* rg = (const float4*)(Wb + (size_t)(j + 2 * H) * H);
    const float4* ro = (const float4*)(Wb + (size_t)(j + 3 * H) * H);

    float gi = 0.0f, gg = 0.0f, go = 0.0f;
    #pragma unroll
    for (int k = lane; k < H / 4; k += 64) {
        float4 h = hs[k];
        float4 a = ri[k]; gi += a.x * h.x + a.y * h.y + a.z * h.z + a.w * h.w;
        float4 c = rg[k]; gg += c.x * h.x + c.y * h.y + c.z * h.z + c.w * h.w;
        float4 d = ro[k]; go += d.x * h.x + d.y * h.y + d.z * h.z + d.w * h.w;
    }
    gi = wave_reduce_sum(gi);
    gg = wave_reduce_sum(gg);
    go = wave_reduce_sum(go);
    if (lane == 0) {
        size_t base = (size_t)b * 4 * H;
        gi += bih1[base + j]         + bhh1[base + j];
        gg += bih1[base + j + 2 * H] + bhh1[base + j + 2 * H];
        go += bih1[base + j + 3 * H] + bhh1[base + j + 3 * H];
        float c2 = sigmoidf_(gi) * tanhf(gg);
        ctx[b * H + j] = sigmoidf_(go) * tanhf(c2);
    }
}

// ---------------------------------------------------------------------------
// Kernel 4: fused = fuse_w @ ctx_flat + fuse_b   (1024 x 5120 matvec)
// one block (256 threads) per output row
// ---------------------------------------------------------------------------
__global__ void fuse_kernel(const float* __restrict__ fuse_w,
                            const float* __restrict__ fuse_b,
                            const float* __restrict__ ctx,
                            float* __restrict__ fused) {
    int row = blockIdx.x;
    const float4* r  = (const float4*)(fuse_w + (size_t)row * (NB * H));
    const float4* c4 = (const float4*)ctx;
    float acc = 0.0f;
    #pragma unroll
    for (int k = threadIdx.x; k < (NB * H) / 4; k += 256) {  // 5 iters
        float4 a = r[k], c = c4[k];
        acc += a.x * c.x + a.y * c.y + a.z * c.z + a.w * c.w;
    }
    acc = wave_reduce_sum(acc);
    __shared__ float red[4];
    int wave = threadIdx.x >> 6, lane = threadIdx.x & 63;
    if (lane == 0) red[wave] = acc;
    __syncthreads();
    if (threadIdx.x == 0) {
        fused[row] = red[0] + red[1] + red[2] + red[3] + fuse_b[row];
    }
}

// ---------------------------------------------------------------------------
// Kernel 5: logits = fc_w @ fused + fc_b   (1000 x 1024 matvec)
// one wave per output row, 4 rows/block, fused staged in LDS
// ---------------------------------------------------------------------------
__global__ void fc_kernel(const float* __restrict__ fc_w,
                          const float* __restrict__ fc_b,
                          const float* __restrict__ fused,
                          float* __restrict__ out) {
    __shared__ float4 fs[H / 4];
    fs[threadIdx.x] = ((const float4*)fused)[threadIdx.x];
    __syncthreads();
    int wave = threadIdx.x >> 6, lane = threadIdx.x & 63;
    int row = blockIdx.x * 4 + wave;  // 250 blocks * 4 = 1000 exactly
    const float4* r = (const float4*)(fc_w + (size_t)row * H);
    float acc = 0.0f;
    #pragma unroll
    for (int k = lane; k < H / 4; k += 64) {
        float4 a = r[k], f = fs[k];
        acc += a.x * f.x + a.y * f.y + a.z * f.z + a.w * f.w;
    }
    acc = wave_reduce_sum(acc);
    if (lane == 0) out[row] = acc + fc_b[row];
}

// ---------------------------------------------------------------------------
extern "C" void kernel_launch(void* const* d_in, const int* in_sizes, int n_in,
                              void* d_out, int out_size, void* d_ws, size_t ws_size,
                              hipStream_t stream) {
    (void)in_sizes; (void)n_in; (void)out_size; (void)ws_size;
    const float* x      = (const float*)d_in[0];
    const float* W_ih0  = (const float*)d_in[1];
    // d_in[2] = W_hh0  : unused (h=0)
    const float* b_ih0  = (const float*)d_in[3];
    const float* b_hh0  = (const float*)d_in[4];
    const float* W_ih1  = (const float*)d_in[5];
    // d_in[6] = W_hh1  : unused (h=0)
    const float* b_ih1  = (const float*)d_in[7];
    const float* b_hh1  = (const float*)d_in[8];
    // d_in[9..12] = Wa, ba, Ws, bs : unused (softmax over 1 element == 1)
    const float* fuse_w = (const float*)d_in[13];
    const float* fuse_b = (const float*)d_in[14];
    const float* fc_w   = (const float*)d_in[15];
    const float* fc_b   = (const float*)d_in[16];
    float* out = (float*)d_out;

    float* ws    = (float*)d_ws;
    float* xb    = ws;            // 210 floats
    float* h0    = ws + 256;      // 5120 floats
    float* ctx   = ws + 5376;     // 5120 floats
    float* fused = ws + 10496;    // 1024 floats

    prep_kernel<<<1, 64, 0, stream>>>(x, xb);
    layer0_kernel<<<1280, 256, 0, stream>>>(W_ih0, b_ih0, b_hh0, xb, h0);
    layer1_kernel<<<1280, 256, 0, stream>>>(W_ih1, b_ih1, b_hh1, h0, ctx);
    fuse_kernel<<<1024, 256, 0, stream>>>(fuse_w, fuse_b, ctx, fused);
    fc_kernel<<<250, 256, 0, stream>>>(fc_w, fc_b, fused, out);
}

// Round 2
// 249.579 us; speedup vs baseline: 1.0002x; 1.0002x over previous
//
#include <hip/hip_runtime.h>
#include <math.h>

#define H 1024
#define NB 5
#define IN 42
#define C_OUT 1000

__device__ __forceinline__ float sigmoidf_(float x) {
    return 1.0f / (1.0f + expf(-x));
}

__device__ __forceinline__ float wave_reduce_sum(float v) {
    #pragma unroll
    for (int off = 32; off > 0; off >>= 1) v += __shfl_xor(v, off);
    return v;
}

// ---------------------------------------------------------------------------
// Kernel 1: prep (fused, per-block recompute) + layer0 LSTM cell (h=c=0).
// Each block handles 4 consecutive outputs of h0 (same branch b).
// g = W_ih0[b] @ xb[b] + b_ih0[b] + b_hh0[b]; f-gate dead (c=0).
// h0 = sigmoid(o) * tanh( sigmoid(i) * tanh(g) )
// ---------------------------------------------------------------------------
__global__ void layer0_kernel(const float* __restrict__ x,
                              const float* __restrict__ wih0,
                              const float* __restrict__ bih0,
                              const float* __restrict__ bhh0,
                              float* __restrict__ h0out) {
    __shared__ float slx[21], sly[21], srx[21], sry[21];
    __shared__ float sxb[IN];

    int out0 = blockIdx.x * 4;
    int b = out0 >> 10;           // branch, uniform per block

    int t = threadIdx.x;
    if (t < 21) {
        slx[t] = x[(91 + t) * 2 + 0];
        sly[t] = x[(91 + t) * 2 + 1];
        srx[t] = x[(112 + t) * 2 + 0];
        sry[t] = x[(112 + t) * 2 + 1];
    }
    __syncthreads();

    if (t < 21) {
        float lx_min = slx[0], lx_max = slx[0], ly_min = sly[0], ly_max = sly[0];
        float rx_min = srx[0], rx_max = srx[0], ry_min = sry[0], ry_max = sry[0];
        #pragma unroll
        for (int i = 1; i < 21; ++i) {
            lx_min = fminf(lx_min, slx[i]); lx_max = fmaxf(lx_max, slx[i]);
            ly_min = fminf(ly_min, sly[i]); ly_max = fmaxf(ly_max, sly[i]);
            rx_min = fminf(rx_min, srx[i]); rx_max = fmaxf(rx_max, srx[i]);
            ry_min = fminf(ry_min, sry[i]); ry_max = fmaxf(ry_max, sry[i]);
        }
        float w_l = lx_max - lx_min, h_l = ly_max - ly_min;
        float w_r = rx_max - rx_min, h_r = ry_max - ry_min;
        float w_b = x[5 * 2 + 0] - x[6 * 2 + 0];
        float h_b = 4.0f * w_b;
        float sbx = x[0], sby = x[1];
        float slx0 = slx[9], sly0 = sly[9];
        float srx0 = srx[9], sry0 = sry[9];
        bool cond_l = (w_l != 0.0f) && (h_l != 0.0f);
        bool cond_r = (w_r != 0.0f) && (h_r != 0.0f);
        bool cond_b = (w_b != 0.0f) && (h_b != 0.0f);
        float dlx = cond_l ? w_l : 1.0f, dly = cond_l ? h_l : 1.0f;
        float drx = cond_r ? w_r : 1.0f, dry = cond_r ? h_r : 1.0f;
        float wb  = cond_b ? w_b : 1.0f, hb  = cond_b ? h_b : 1.0f;

        float lx = slx[t], ly = sly[t], rx = srx[t], ry = sry[t];
        float vx, vy;
        switch (b) {
            case 0: vx = (lx - slx0) / dlx; vy = (ly - sly0) / dly; break;
            case 1: vx = (rx - srx0) / drx; vy = (ry - sry0) / dry; break;
            case 2: vx = (lx - sbx) / wb;   vy = (ly - sby);        break;
            case 3: vx = (rx - sbx);        vy = (ry - sby) / hb;   break;
            default:vx = (lx - rx) / wb;    vy = (ly - ry) / hb;    break;
        }
        sxb[2 * t + 0] = vx;
        sxb[2 * t + 1] = vy;
    }
    __syncthreads();

    int wave = t >> 6;
    int lane = t & 63;
    int j = (out0 + wave) & (H - 1);

    float xv = (lane < IN) ? sxb[lane] : 0.0f;
    const float* Wb = wih0 + (size_t)b * 4 * H * IN;
    float gi = 0.0f, gg = 0.0f, go = 0.0f;
    if (lane < IN) {
        gi = Wb[(size_t)(j)         * IN + lane] * xv;
        gg = Wb[(size_t)(j + 2 * H) * IN + lane] * xv;
        go = Wb[(size_t)(j + 3 * H) * IN + lane] * xv;
    }
    gi = wave_reduce_sum(gi);
    gg = wave_reduce_sum(gg);
    go = wave_reduce_sum(go);
    if (lane == 0) {
        size_t base = (size_t)b * 4 * H;
        gi += bih0[base + j]         + bhh0[base + j];
        gg += bih0[base + j + 2 * H] + bhh0[base + j + 2 * H];
        go += bih0[base + j + 3 * H] + bhh0[base + j + 3 * H];
        float c2 = sigmoidf_(gi) * tanhf(gg);
        h0out[b * H + j] = sigmoidf_(go) * tanhf(c2);
    }
}

// ---------------------------------------------------------------------------
// Kernel 2: layer1 LSTM cell (h=c=0): one wave per output, 8 outputs/block
// (512 threads). h0[b] staged in LDS. ctx = h1 (softmax over 1 elem == 1).
// ---------------------------------------------------------------------------
__global__ void layer1_kernel(const float* __restrict__ wih1,
                              const float* __restrict__ bih1,
                              const float* __restrict__ bhh1,
                              const float* __restrict__ h0,
                              float* __restrict__ ctx) {
    __shared__ float4 hs[H / 4];  // 1024 floats
    int out0 = blockIdx.x * 8;            // first output of this block
    int b = out0 >> 10;                   // uniform per block (1024 % 8 == 0)
    if (threadIdx.x < H / 4)
        hs[threadIdx.x] = ((const float4*)(h0 + b * H))[threadIdx.x];
    __syncthreads();

    int wave = threadIdx.x >> 6;
    int lane = threadIdx.x & 63;
    int j = (out0 + wave) & (H - 1);

    const float* Wb = wih1 + (size_t)b * 4 * H * H;
    const float4* ri = (const float4*)(Wb + (size_t)(j)         * H);
    const float4* rg = (const float4*)(Wb + (size_t)(j + 2 * H) * H);
    const float4* ro = (const float4*)(Wb + (size_t)(j + 3 * H) * H);

    float gi = 0.0f, gg = 0.0f, go = 0.0f;
    #pragma unroll
    for (int k = lane; k < H / 4; k += 64) {
        float4 h = hs[k];
        float4 a = ri[k]; gi += a.x * h.x + a.y * h.y + a.z * h.z + a.w * h.w;
        float4 c = rg[k]; gg += c.x * h.x + c.y * h.y + c.z * h.z + c.w * h.w;
        float4 d = ro[k]; go += d.x * h.x + d.y * h.y + d.z * h.z + d.w * h.w;
    }
    gi = wave_reduce_sum(gi);
    gg = wave_reduce_sum(gg);
    go = wave_reduce_sum(go);
    if (lane == 0) {
        size_t base = (size_t)b * 4 * H;
        gi += bih1[base + j]         + bhh1[base + j];
        gg += bih1[base + j + 2 * H] + bhh1[base + j + 2 * H];
        go += bih1[base + j + 3 * H] + bhh1[base + j + 3 * H];
        float c2 = sigmoidf_(gi) * tanhf(gg);
        ctx[b * H + j] = sigmoidf_(go) * tanhf(c2);
    }
}

// ---------------------------------------------------------------------------
// Kernel 3: fused = fuse_w @ ctx_flat + fuse_b   (1024 x 5120 matvec)
// one block (256 threads) per output row
// ---------------------------------------------------------------------------
__global__ void fuse_kernel(const float* __restrict__ fuse_w,
                            const float* __restrict__ fuse_b,
                            const float* __restrict__ ctx,
                            float* __restrict__ fused) {
    int row = blockIdx.x;
    const float4* r  = (const float4*)(fuse_w + (size_t)row * (NB * H));
    const float4* c4 = (const float4*)ctx;
    float acc = 0.0f;
    #pragma unroll
    for (int k = threadIdx.x; k < (NB * H) / 4; k += 256) {  // 5 iters
        float4 a = r[k], c = c4[k];
        acc += a.x * c.x + a.y * c.y + a.z * c.z + a.w * c.w;
    }
    acc = wave_reduce_sum(acc);
    __shared__ float red[4];
    int wave = threadIdx.x >> 6, lane = threadIdx.x & 63;
    if (lane == 0) red[wave] = acc;
    __syncthreads();
    if (threadIdx.x == 0) {
        fused[row] = red[0] + red[1] + red[2] + red[3] + fuse_b[row];
    }
}

// ---------------------------------------------------------------------------
// Kernel 4: logits = fc_w @ fused + fc_b   (1000 x 1024 matvec)
// one wave per output row, 4 rows/block, fused staged in LDS
// ---------------------------------------------------------------------------
__global__ void fc_kernel(const float* __restrict__ fc_w,
                          const float* __restrict__ fc_b,
                          const float* __restrict__ fused,
                          float* __restrict__ out) {
    __shared__ float4 fs[H / 4];
    fs[threadIdx.x] = ((const float4*)fused)[threadIdx.x];
    __syncthreads();
    int wave = threadIdx.x >> 6, lane = threadIdx.x & 63;
    int row = blockIdx.x * 4 + wave;  // 250 blocks * 4 = 1000 exactly
    const float4* r = (const float4*)(fc_w + (size_t)row * H);
    float acc = 0.0f;
    #pragma unroll
    for (int k = lane; k < H / 4; k += 64) {
        float4 a = r[k], f = fs[k];
        acc += a.x * f.x + a.y * f.y + a.z * f.z + a.w * f.w;
    }
    acc = wave_reduce_sum(acc);
    if (lane == 0) out[row] = acc + fc_b[row];
}

// ---------------------------------------------------------------------------
extern "C" void kernel_launch(void* const* d_in, const int* in_sizes, int n_in,
                              void* d_out, int out_size, void* d_ws, size_t ws_size,
                              hipStream_t stream) {
    (void)in_sizes; (void)n_in; (void)out_size; (void)ws_size;
    const float* x      = (const float*)d_in[0];
    const float* W_ih0  = (const float*)d_in[1];
    // d_in[2] = W_hh0  : unused (h=0 at t=0)
    const float* b_ih0  = (const float*)d_in[3];
    const float* b_hh0  = (const float*)d_in[4];
    const float* W_ih1  = (const float*)d_in[5];
    // d_in[6] = W_hh1  : unused (h=0 at t=0)
    const float* b_ih1  = (const float*)d_in[7];
    const float* b_hh1  = (const float*)d_in[8];
    // d_in[9..12] = Wa, ba, Ws, bs : unused (softmax over 1 element == 1)
    const float* fuse_w = (const float*)d_in[13];
    const float* fuse_b = (const float*)d_in[14];
    const float* fc_w   = (const float*)d_in[15];
    const float* fc_b   = (const float*)d_in[16];
    float* out = (float*)d_out;

    float* ws    = (float*)d_ws;
    float* h0    = ws;            // 5120 floats
    float* ctx   = ws + 5120;     // 5120 floats
    float* fused = ws + 10240;    // 1024 floats

    layer0_kernel<<<1280, 256, 0, stream>>>(x, W_ih0, b_ih0, b_hh0, h0);
    layer1_kernel<<<640, 512, 0, stream>>>(W_ih1, b_ih1, b_hh1, h0, ctx);
    fuse_kernel<<<1024, 256, 0, stream>>>(fuse_w, fuse_b, ctx, fused);
    fc_kernel<<<250, 256, 0, stream>>>(fc_w, fc_b, fused, out);
}